// Round 4
// baseline (379.665 us; speedup 1.0000x reference)
//
#include <hip/hip_runtime.h>
#include <hip/hip_bf16.h>
#include <type_traits>

// GroupedQueryAttention: B=2, S=2048, H=2048, NH=32, NKV=8, HD=64, G=4
// Pipeline:
//   1. hs -> bf16
//   2. transpose+cvt weights to [N][K] bf16 (B^T layout for GEMM)
//   3. Q = hs@wq (N=2048), KV = hs@[wk|wv] (N=1024, merged)
//   3b. V -> V^T  ([b][kvh][d][s]) for MFMA PV step
//   4. MFMA flash attention: causal-paired q-tiles, double-buffered K/V
//   5. out = attn@wo (fp32 out)

#define B_SZ 2
#define S_LEN 2048
#define HID 2048
#define NHEADS 32
#define NKVH 8
#define HEADD 64
#define ATT_SCALE 0.125f  // 64^-0.5

typedef __attribute__((ext_vector_type(8))) short bf16x8;
typedef __attribute__((ext_vector_type(4))) float f32x4;

__device__ __forceinline__ float bf2f(unsigned short u) {
  union { unsigned int i; float f; } v;
  v.i = ((unsigned int)u) << 16;
  return v.f;
}
__device__ __forceinline__ unsigned short f2bf(float f) {
  union { float f; unsigned int i; } v;
  v.f = f;
  unsigned int r = v.i + 0x7fffu + ((v.i >> 16) & 1u);
  return (unsigned short)(r >> 16);
}
// async global->LDS, 16B per lane; lds dest = wave-uniform base + lane*16
__device__ __forceinline__ void gload_lds16(const unsigned short* g, unsigned short* l) {
  __builtin_amdgcn_global_load_lds(
      (const __attribute__((address_space(1))) unsigned int*)g,
      (__attribute__((address_space(3))) unsigned int*)l, 16, 0, 0);
}

// ---------------- elementwise f32 -> bf16 ----------------
__global__ void cvt_bf16_kernel(const float4* __restrict__ in,
                                ushort4* __restrict__ out, int n4) {
  int i = blockIdx.x * blockDim.x + threadIdx.x;
  if (i >= n4) return;
  float4 v = in[i];
  ushort4 o;
  o.x = f2bf(v.x); o.y = f2bf(v.y); o.z = f2bf(v.z); o.w = f2bf(v.w);
  out[i] = o;
}

// ---------------- transpose + cvt: in[R][C] f32 -> out[C][R] bf16 ----------------
__global__ void transpose_cvt_kernel(const float* __restrict__ in,
                                     unsigned short* __restrict__ out,
                                     int R, int C) {
  __shared__ float tile[32][33];
  int c0 = blockIdx.x * 32, r0 = blockIdx.y * 32;
  int x = threadIdx.x, y = threadIdx.y;
#pragma unroll
  for (int i = 0; i < 32; i += 8)
    tile[y + i][x] = in[(size_t)(r0 + y + i) * C + c0 + x];
  __syncthreads();
#pragma unroll
  for (int i = 0; i < 32; i += 8)
    out[(size_t)(c0 + y + i) * R + r0 + x] = f2bf(tile[x][y + i]);
}

// ---------------- bf16 transpose: KV[b,s,512+kvh*64+d] -> Vt[(b*8+kvh)*64+d][s] ----
__global__ void transpose_v_kernel(const unsigned short* __restrict__ KVb,
                                   unsigned short* __restrict__ Vt) {
  __shared__ unsigned short tile[32][33];
  int s0 = blockIdx.x * 32, d0 = blockIdx.y * 32;
  int bk = blockIdx.z;
  int b = bk >> 3, kvh = bk & 7;
  int x = threadIdx.x, y = threadIdx.y;
#pragma unroll
  for (int i = 0; i < 32; i += 8)
    tile[y + i][x] =
        KVb[(size_t)(b * S_LEN + s0 + y + i) * 1024 + 512 + kvh * HEADD + d0 + x];
  __syncthreads();
#pragma unroll
  for (int i = 0; i < 32; i += 8)
    Vt[((size_t)(b * NKVH + kvh) * HEADD + d0 + y + i) * S_LEN + s0 + x] =
        tile[x][y + i];
}

// ---------------- bf16 MFMA GEMM: C[M][N] = A[M][K] * Bt[N][K]^T ----------------
// 128x128 tile, BK=32, 4 waves; staging via global_load_lds (width=16, linear LDS).
template <typename OutT>
__global__ __launch_bounds__(256) void gemm_bt_kernel(
    const unsigned short* __restrict__ A, const unsigned short* __restrict__ Bt,
    OutT* __restrict__ C, int M, int N, int K) {
  __shared__ unsigned short ldsA[128 * 32];
  __shared__ unsigned short ldsB[128 * 32];
  const int tid = threadIdx.x;
  const int wave = tid >> 6;
  const int lane = tid & 63;
  const int m0 = blockIdx.y * 128;
  const int n0 = blockIdx.x * 128;
  const int wr = wave >> 1, wc = wave & 1;
  f32x4 acc[4][4] = {};

  for (int k0 = 0; k0 < K; k0 += 32) {
    __syncthreads();  // all waves done reading previous tile
#pragma unroll
    for (int i = 0; i < 2; ++i) {
      int c = tid + i * 256;
      int row = c >> 2;
      int kc = (c & 3) * 8;
      // LDS dest: chunk c*16B == (wave*64 + i*256)*16B + lane*16B  (linear)
      gload_lds16(A + (size_t)(m0 + row) * K + k0 + kc,
                  &ldsA[(wave * 64 + i * 256) * 8]);
      gload_lds16(Bt + (size_t)(n0 + row) * K + k0 + kc,
                  &ldsB[(wave * 64 + i * 256) * 8]);
    }
    __syncthreads();  // compiler drains vmcnt before this barrier
    const int kq = (lane >> 4) * 8;
    const int rl = lane & 15;
    bf16x8 a[4], b[4];
#pragma unroll
    for (int mi = 0; mi < 4; ++mi)
      a[mi] = *(const bf16x8*)&ldsA[(wr * 64 + mi * 16 + rl) * 32 + kq];
#pragma unroll
    for (int ni = 0; ni < 4; ++ni)
      b[ni] = *(const bf16x8*)&ldsB[(wc * 64 + ni * 16 + rl) * 32 + kq];
#pragma unroll
    for (int mi = 0; mi < 4; ++mi)
#pragma unroll
      for (int ni = 0; ni < 4; ++ni)
        acc[mi][ni] =
            __builtin_amdgcn_mfma_f32_16x16x32_bf16(a[mi], b[ni], acc[mi][ni], 0, 0, 0);
  }
#pragma unroll
  for (int mi = 0; mi < 4; ++mi)
#pragma unroll
    for (int ni = 0; ni < 4; ++ni)
#pragma unroll
      for (int r = 0; r < 4; ++r) {
        int row = m0 + wr * 64 + mi * 16 + (lane >> 4) * 4 + r;
        int col = n0 + wc * 64 + ni * 16 + (lane & 15);
        float v = acc[mi][ni][r];
        if constexpr (std::is_same_v<OutT, unsigned short>)
          C[(size_t)row * N + col] = f2bf(v);
        else
          C[(size_t)row * N + col] = v;
      }
}

// ---------------- MFMA flash attention, causal-paired + double-buffered ----------
// grid: (16 pairs, NH, B). block 256 = 4 waves; wave w owns 16 q-rows.
// Block processes q-tiles {x, 31-x} sequentially => constant 33 KV-tile iters.
// K/V LDS double-buffered; next tile's global loads issued before compute (T14).
// NOTE: no min-occupancy launch_bounds arg — (256,4) capped VGPRs at ~64 and
// caused ~430 MB/dispatch scratch spill traffic (R3 post-mortem).
__global__ __launch_bounds__(256) void mfma_attn_kernel(
    const unsigned short* __restrict__ Q,    // [B*S][NH*64]
    const unsigned short* __restrict__ KVb,  // [B*S][1024]; K at col kvh*64
    const unsigned short* __restrict__ Vt,   // [(b*8+kvh)*64+d][S]
    unsigned short* __restrict__ O) {        // [B*S][NH*64]
  __shared__ unsigned short Ks[2][64 * 64];
  __shared__ unsigned short Vs[2][64 * 64];
  __shared__ unsigned short Pl[4 * 16 * 64];
  const int head = blockIdx.y, b = blockIdx.z;
  const int kvh = head >> 2;
  const int tid = threadIdx.x;
  const int w = tid >> 6, lane = tid & 63;
  const int c = lane & 15, g = lane >> 4;
  unsigned short* Plw = Pl + w * 1024;
  const int srow = tid >> 3, sslot = tid & 7;

  const unsigned short* Kbase =
      KVb + (size_t)b * S_LEN * 1024 + kvh * HEADD + sslot * 8;
  const unsigned short* Vbase =
      Vt + ((size_t)(b * NKVH + kvh) * HEADD + srow) * S_LEN + sslot * 8;

  const int qts[2] = {(int)blockIdx.x, (S_LEN / 64 - 1) - (int)blockIdx.x};
  int4 kreg[2], vreg[2];
  int cur = 0;

  // prologue: stage tile 0 (phase 0)
#pragma unroll
  for (int i = 0; i < 2; ++i) {
    kreg[i] = *(const int4*)(Kbase + (size_t)(srow + i * 32) * 1024);
    vreg[i] = *(const int4*)(Vbase + (size_t)(i * 32) * S_LEN);
  }
#pragma unroll
  for (int i = 0; i < 2; ++i) {
    int row = srow + i * 32;
    int sw = (sslot ^ (row & 7)) * 8;
    *(int4*)&Ks[0][row * 64 + sw] = kreg[i];
    *(int4*)&Vs[0][row * 64 + sw] = vreg[i];
  }
  __syncthreads();

  for (int ph = 0; ph < 2; ++ph) {
    const int qt = qts[ph];
    bf16x8 qf[2];
    {
      const unsigned short* qp =
          Q + (size_t)(b * S_LEN + qt * 64 + w * 16 + c) * (NHEADS * HEADD) +
          head * HEADD + g * 8;
      qf[0] = *(const bf16x8*)(qp);
      qf[1] = *(const bf16x8*)(qp + 32);
    }
    f32x4 o_acc[4] = {};
    float mstate[4], lstate[4];
#pragma unroll
    for (int r = 0; r < 4; ++r) { mstate[r] = -INFINITY; lstate[r] = 0.f; }

    for (int t = 0; t <= qt; ++t) {
      const int kv0 = t * 64;
      const bool has_next = !(ph == 1 && t == qt);
      if (has_next) {
        const int kv0n = (t < qt) ? kv0 + 64 : 0;
#pragma unroll
        for (int i = 0; i < 2; ++i) {
          kreg[i] = *(const int4*)(Kbase + (size_t)(kv0n + srow + i * 32) * 1024);
          vreg[i] = *(const int4*)(Vbase + (size_t)(i * 32) * S_LEN + kv0n);
        }
      }
      // ---- QK^T: S[16 q][64 kv] per wave ----
      f32x4 s_acc[4] = {};
#pragma unroll
      for (int ks = 0; ks < 2; ++ks)
#pragma unroll
        for (int kn = 0; kn < 4; ++kn) {
          bf16x8 bf = *(const bf16x8*)&Ks[cur][(kn * 16 + c) * 64 +
                                              (((ks * 4 + g) ^ (c & 7)) * 8)];
          s_acc[kn] =
              __builtin_amdgcn_mfma_f32_16x16x32_bf16(qf[ks], bf, s_acc[kn], 0, 0, 0);
        }
      // ---- scale + causal mask ----
      float s[4][4];
#pragma unroll
      for (int kn = 0; kn < 4; ++kn)
#pragma unroll
        for (int r = 0; r < 4; ++r) s[kn][r] = s_acc[kn][r] * ATT_SCALE;
      if (t == qt) {
#pragma unroll
        for (int kn = 0; kn < 4; ++kn)
#pragma unroll
          for (int r = 0; r < 4; ++r)
            if (kv0 + kn * 16 + c > qt * 64 + w * 16 + g * 4 + r) s[kn][r] = -1e30f;
      }
      // ---- online softmax ----
      float mx[4];
#pragma unroll
      for (int r = 0; r < 4; ++r)
        mx[r] = fmaxf(fmaxf(s[0][r], s[1][r]), fmaxf(s[2][r], s[3][r]));
#pragma unroll
      for (int r = 0; r < 4; ++r) {
        mx[r] = fmaxf(mx[r], __shfl_xor(mx[r], 1));
        mx[r] = fmaxf(mx[r], __shfl_xor(mx[r], 2));
        mx[r] = fmaxf(mx[r], __shfl_xor(mx[r], 4));
        mx[r] = fmaxf(mx[r], __shfl_xor(mx[r], 8));
      }
      float alpha[4];
#pragma unroll
      for (int r = 0; r < 4; ++r) {
        float nm = fmaxf(mstate[r], mx[r]);
        alpha[r] = __expf(mstate[r] - nm);
        mstate[r] = nm;
      }
      float rsum[4] = {0.f, 0.f, 0.f, 0.f};
#pragma unroll
      for (int kn = 0; kn < 4; ++kn)
#pragma unroll
        for (int r = 0; r < 4; ++r) {
          float p = __expf(s[kn][r] - mstate[r]);
          unsigned short pb = f2bf(p);
          rsum[r] += bf2f(pb);
          int q = g * 4 + r, k = kn * 16 + c;
          Plw[q * 64 + (k ^ ((q & 7) << 3))] = pb;
        }
#pragma unroll
      for (int r = 0; r < 4; ++r) {
        rsum[r] += __shfl_xor(rsum[r], 1);
        rsum[r] += __shfl_xor(rsum[r], 2);
        rsum[r] += __shfl_xor(rsum[r], 4);
        rsum[r] += __shfl_xor(rsum[r], 8);
        lstate[r] = lstate[r] * alpha[r] + rsum[r];
      }
#pragma unroll
      for (int dn = 0; dn < 4; ++dn)
#pragma unroll
        for (int r = 0; r < 4; ++r) o_acc[dn][r] *= alpha[r];
      // ---- PV: O[16 q][64 d] += P[16][64] @ V^T ----
      bf16x8 af[2];
#pragma unroll
      for (int ks2 = 0; ks2 < 2; ++ks2)
        af[ks2] = *(const bf16x8*)&Plw[c * 64 + ((ks2 * 32 + g * 8) ^ ((c & 7) << 3))];
#pragma unroll
      for (int ks2 = 0; ks2 < 2; ++ks2)
#pragma unroll
        for (int dn = 0; dn < 4; ++dn) {
          bf16x8 vf = *(const bf16x8*)&Vs[cur][(dn * 16 + c) * 64 +
                                              (((ks2 * 4 + g) ^ (c & 7)) * 8)];
          o_acc[dn] =
              __builtin_amdgcn_mfma_f32_16x16x32_bf16(af[ks2], vf, o_acc[dn], 0, 0, 0);
        }
      __syncthreads();  // all waves done reading buf[cur]
      if (has_next) {
#pragma unroll
        for (int i = 0; i < 2; ++i) {
          int row = srow + i * 32;
          int sw = (sslot ^ (row & 7)) * 8;
          *(int4*)&Ks[cur ^ 1][row * 64 + sw] = kreg[i];
          *(int4*)&Vs[cur ^ 1][row * 64 + sw] = vreg[i];
        }
        __syncthreads();  // writes visible
        cur ^= 1;
      }
    }
    // ---- epilogue for this phase ----
    float inv[4];
#pragma unroll
    for (int r = 0; r < 4; ++r) inv[r] = 1.0f / lstate[r];
#pragma unroll
    for (int dn = 0; dn < 4; ++dn)
#pragma unroll
      for (int r = 0; r < 4; ++r) {
        int row = qt * 64 + w * 16 + g * 4 + r;
        int col = head * HEADD + dn * 16 + c;
        O[(size_t)(b * S_LEN + row) * (NHEADS * HEADD) + col] =
            f2bf(o_acc[dn][r] * inv[r]);
      }
  }
}

extern "C" void kernel_launch(void* const* d_in, const int* in_sizes, int n_in,
                              void* d_out, int out_size, void* d_ws, size_t ws_size,
                              hipStream_t stream) {
  const float* hs = (const float*)d_in[0];
  // d_in[1] = attention_mask: guaranteed causal; implemented analytically
  const float* wq = (const float*)d_in[2];
  const float* wk = (const float*)d_in[3];
  const float* wv = (const float*)d_in[4];
  const float* wo = (const float*)d_in[5];
  float* out = (float*)d_out;

  char* ws = (char*)d_ws;
  unsigned short* hs_bf = (unsigned short*)(ws);                        // 16 MB
  unsigned short* wqT  = (unsigned short*)(ws + ((size_t)16 << 20));    // 8 MB
  unsigned short* wkT  = (unsigned short*)(ws + ((size_t)24 << 20));    // 2 MB (K rows)
  unsigned short* wvT  = (unsigned short*)(ws + ((size_t)26 << 20));    // 2 MB (V rows, contiguous after wkT)
  unsigned short* woT  = (unsigned short*)(ws + ((size_t)28 << 20));    // 8 MB
  unsigned short* Qb   = (unsigned short*)(ws + ((size_t)36 << 20));    // 16 MB
  unsigned short* KVb  = (unsigned short*)(ws + ((size_t)52 << 20));    // 8 MB
  unsigned short* Ab   = (unsigned short*)(ws + ((size_t)60 << 20));    // 16 MB
  unsigned short* VtB  = (unsigned short*)(ws + ((size_t)76 << 20));    // 4 MB

  // 1. hs -> bf16
  int n4 = (B_SZ * S_LEN * HID) / 4;
  cvt_bf16_kernel<<<n4 / 256, 256, 0, stream>>>((const float4*)hs, (ushort4*)hs_bf, n4);

  // 2. weight transposes ([K][N] f32 -> [N][K] bf16)
  dim3 tb(32, 8);
  transpose_cvt_kernel<<<dim3(64, 64), tb, 0, stream>>>(wq, wqT, HID, NHEADS * HEADD);
  transpose_cvt_kernel<<<dim3(16, 64), tb, 0, stream>>>(wk, wkT, HID, NKVH * HEADD);
  transpose_cvt_kernel<<<dim3(16, 64), tb, 0, stream>>>(wv, wvT, HID, NKVH * HEADD);
  transpose_cvt_kernel<<<dim3(64, 64), tb, 0, stream>>>(wo, woT, NHEADS * HEADD, HID);

  // 3. projections: Q (N=2048) and merged KV (N=1024; wkT||wvT contiguous)
  gemm_bt_kernel<unsigned short><<<dim3(16, 32), 256, 0, stream>>>(
      hs_bf, wqT, Qb, B_SZ * S_LEN, NHEADS * HEADD, HID);
  gemm_bt_kernel<unsigned short><<<dim3(8, 32), 256, 0, stream>>>(
      hs_bf, wkT, KVb, B_SZ * S_LEN, 1024, HID);

  // 3b. V -> V^T
  transpose_v_kernel<<<dim3(S_LEN / 32, HEADD / 32, B_SZ * NKVH), tb, 0, stream>>>(
      KVb, VtB);

  // 4. attention (MFMA flash, paired + double-buffered)
  mfma_attn_kernel<<<dim3(S_LEN / 128, NHEADS, B_SZ), 256, 0, stream>>>(
      Qb, KVb, VtB, Ab);

  // 5. output projection (fp32 out)
  gemm_bt_kernel<float><<<dim3(16, 32), 256, 0, stream>>>(
      Ab, woT, out, B_SZ * S_LEN, HID, HID);
}

// Round 5
// 315.801 us; speedup vs baseline: 1.2022x; 1.2022x over previous
//
#include <hip/hip_runtime.h>
#include <hip/hip_bf16.h>
#include <type_traits>

// GroupedQueryAttention: B=2, S=2048, H=2048, NH=32, NKV=8, HD=64, G=4
// Pipeline:
//   1. hs -> bf16
//   2. transpose+cvt weights to [N][K] bf16 (B^T layout for GEMM)
//   3. Q = hs@wq (N=2048), KV = hs@[wk|wv] (N=1024, merged)
//   3b. V -> V^T  ([b][kvh][d][s]) for MFMA PV step
//   4. MFMA flash attention: causal-paired q-tiles, double-buffered K/V staged
//      via global_load_lds with pre-swizzled global source (rule #21 / m173)
//   5. out = attn@wo (fp32 out)

#define B_SZ 2
#define S_LEN 2048
#define HID 2048
#define NHEADS 32
#define NKVH 8
#define HEADD 64
#define ATT_SCALE 0.125f  // 64^-0.5

typedef __attribute__((ext_vector_type(8))) short bf16x8;
typedef __attribute__((ext_vector_type(4))) float f32x4;

__device__ __forceinline__ float bf2f(unsigned short u) {
  union { unsigned int i; float f; } v;
  v.i = ((unsigned int)u) << 16;
  return v.f;
}
__device__ __forceinline__ unsigned short f2bf(float f) {
  union { float f; unsigned int i; } v;
  v.f = f;
  unsigned int r = v.i + 0x7fffu + ((v.i >> 16) & 1u);
  return (unsigned short)(r >> 16);
}
// async global->LDS, 16B per lane; lds dest = wave-uniform base + lane*16
__device__ __forceinline__ void gload_lds16(const unsigned short* g, unsigned short* l) {
  __builtin_amdgcn_global_load_lds(
      (const __attribute__((address_space(1))) unsigned int*)g,
      (__attribute__((address_space(3))) unsigned int*)l, 16, 0, 0);
}

// ---------------- elementwise f32 -> bf16 ----------------
__global__ void cvt_bf16_kernel(const float4* __restrict__ in,
                                ushort4* __restrict__ out, int n4) {
  int i = blockIdx.x * blockDim.x + threadIdx.x;
  if (i >= n4) return;
  float4 v = in[i];
  ushort4 o;
  o.x = f2bf(v.x); o.y = f2bf(v.y); o.z = f2bf(v.z); o.w = f2bf(v.w);
  out[i] = o;
}

// ---------------- transpose + cvt: in[R][C] f32 -> out[C][R] bf16 ----------------
__global__ void transpose_cvt_kernel(const float* __restrict__ in,
                                     unsigned short* __restrict__ out,
                                     int R, int C) {
  __shared__ float tile[32][33];
  int c0 = blockIdx.x * 32, r0 = blockIdx.y * 32;
  int x = threadIdx.x, y = threadIdx.y;
#pragma unroll
  for (int i = 0; i < 32; i += 8)
    tile[y + i][x] = in[(size_t)(r0 + y + i) * C + c0 + x];
  __syncthreads();
#pragma unroll
  for (int i = 0; i < 32; i += 8)
    out[(size_t)(c0 + y + i) * R + r0 + x] = f2bf(tile[x][y + i]);
}

// ---------------- bf16 transpose: KV[b,s,512+kvh*64+d] -> Vt[(b*8+kvh)*64+d][s] ----
__global__ void transpose_v_kernel(const unsigned short* __restrict__ KVb,
                                   unsigned short* __restrict__ Vt) {
  __shared__ unsigned short tile[32][33];
  int s0 = blockIdx.x * 32, d0 = blockIdx.y * 32;
  int bk = blockIdx.z;
  int b = bk >> 3, kvh = bk & 7;
  int x = threadIdx.x, y = threadIdx.y;
#pragma unroll
  for (int i = 0; i < 32; i += 8)
    tile[y + i][x] =
        KVb[(size_t)(b * S_LEN + s0 + y + i) * 1024 + 512 + kvh * HEADD + d0 + x];
  __syncthreads();
#pragma unroll
  for (int i = 0; i < 32; i += 8)
    Vt[((size_t)(b * NKVH + kvh) * HEADD + d0 + y + i) * S_LEN + s0 + x] =
        tile[x][y + i];
}

// ---------------- bf16 MFMA GEMM: C[M][N] = A[M][K] * Bt[N][K]^T ----------------
// 128x128 tile, BK=32, 4 waves; staging via global_load_lds (width=16, linear LDS).
template <typename OutT>
__global__ __launch_bounds__(256) void gemm_bt_kernel(
    const unsigned short* __restrict__ A, const unsigned short* __restrict__ Bt,
    OutT* __restrict__ C, int M, int N, int K) {
  __shared__ unsigned short ldsA[128 * 32];
  __shared__ unsigned short ldsB[128 * 32];
  const int tid = threadIdx.x;
  const int wave = tid >> 6;
  const int lane = tid & 63;
  const int m0 = blockIdx.y * 128;
  const int n0 = blockIdx.x * 128;
  const int wr = wave >> 1, wc = wave & 1;
  f32x4 acc[4][4] = {};

  for (int k0 = 0; k0 < K; k0 += 32) {
    __syncthreads();  // all waves done reading previous tile
#pragma unroll
    for (int i = 0; i < 2; ++i) {
      int c = tid + i * 256;
      int row = c >> 2;
      int kc = (c & 3) * 8;
      gload_lds16(A + (size_t)(m0 + row) * K + k0 + kc,
                  &ldsA[(wave * 64 + i * 256) * 8]);
      gload_lds16(Bt + (size_t)(n0 + row) * K + k0 + kc,
                  &ldsB[(wave * 64 + i * 256) * 8]);
    }
    __syncthreads();  // compiler drains vmcnt before this barrier
    const int kq = (lane >> 4) * 8;
    const int rl = lane & 15;
    bf16x8 a[4], b[4];
#pragma unroll
    for (int mi = 0; mi < 4; ++mi)
      a[mi] = *(const bf16x8*)&ldsA[(wr * 64 + mi * 16 + rl) * 32 + kq];
#pragma unroll
    for (int ni = 0; ni < 4; ++ni)
      b[ni] = *(const bf16x8*)&ldsB[(wc * 64 + ni * 16 + rl) * 32 + kq];
#pragma unroll
    for (int mi = 0; mi < 4; ++mi)
#pragma unroll
      for (int ni = 0; ni < 4; ++ni)
        acc[mi][ni] =
            __builtin_amdgcn_mfma_f32_16x16x32_bf16(a[mi], b[ni], acc[mi][ni], 0, 0, 0);
  }
#pragma unroll
  for (int mi = 0; mi < 4; ++mi)
#pragma unroll
    for (int ni = 0; ni < 4; ++ni)
#pragma unroll
      for (int r = 0; r < 4; ++r) {
        int row = m0 + wr * 64 + mi * 16 + (lane >> 4) * 4 + r;
        int col = n0 + wc * 64 + ni * 16 + (lane & 15);
        float v = acc[mi][ni][r];
        if constexpr (std::is_same_v<OutT, unsigned short>)
          C[(size_t)row * N + col] = f2bf(v);
        else
          C[(size_t)row * N + col] = v;
      }
}

// ---------------- MFMA flash attention ----------------
// grid: (16 pairs, NH, B). block 256 = 4 waves; wave w owns 16 q-rows.
// Block processes q-tiles {x, 31-x} => constant 33 KV-tile iters (load balance).
// K/V double-buffered in LDS via global_load_lds: stage buf^1 -> compute buf ->
// one barrier -> flip. Global source pre-swizzled so linear LDS dest + swizzled
// reads are consistent (rule #21). No prefetch registers -> no spills (R4 PM).
__global__ __launch_bounds__(256) void mfma_attn_kernel(
    const unsigned short* __restrict__ Q,    // [B*S][NH*64]
    const unsigned short* __restrict__ KVb,  // [B*S][1024]; K at col kvh*64
    const unsigned short* __restrict__ Vt,   // [(b*8+kvh)*64+d][S]
    unsigned short* __restrict__ O) {        // [B*S][NH*64]
  __shared__ unsigned short Ks[2][64 * 64];
  __shared__ unsigned short Vs[2][64 * 64];
  __shared__ unsigned short Pl[4 * 16 * 64];
  const int head = blockIdx.y, b = blockIdx.z;
  const int kvh = head >> 2;
  const int tid = threadIdx.x;
  const int w = tid >> 6, lane = tid & 63;
  const int c = lane & 15, g = lane >> 4;
  unsigned short* Plw = Pl + w * 1024;
  const int srow = tid >> 3, sslot = tid & 7;
  const int xslot = sslot ^ (srow & 7);  // (row+32)&7 == row&7, so same for both i

  // pre-swizzled per-lane global sources; LDS dest stays linear
  const unsigned short* Ksrc[2];
  const unsigned short* Vsrc[2];
#pragma unroll
  for (int i = 0; i < 2; ++i) {
    int row = srow + i * 32;
    Ksrc[i] = KVb + (size_t)(b * S_LEN + row) * 1024 + kvh * HEADD + xslot * 8;
    Vsrc[i] = Vt + ((size_t)(b * NKVH + kvh) * HEADD + row) * S_LEN + xslot * 8;
  }

  // prologue: stage tile 0 into buf 0
#pragma unroll
  for (int i = 0; i < 2; ++i) {
    gload_lds16(Ksrc[i], &Ks[0][(w * 64 + i * 256) * 8]);
    gload_lds16(Vsrc[i], &Vs[0][(w * 64 + i * 256) * 8]);
  }
  __syncthreads();
  int cur = 0;

  for (int ph = 0; ph < 2; ++ph) {
    const int qt = (ph == 0) ? (int)blockIdx.x : (S_LEN / 64 - 1) - (int)blockIdx.x;
    bf16x8 qf[2];
    {
      const unsigned short* qp =
          Q + (size_t)(b * S_LEN + qt * 64 + w * 16 + c) * (NHEADS * HEADD) +
          head * HEADD + g * 8;
      qf[0] = *(const bf16x8*)(qp);
      qf[1] = *(const bf16x8*)(qp + 32);
    }
    f32x4 o_acc[4] = {};
    float mstate[4], lstate[4];
#pragma unroll
    for (int r = 0; r < 4; ++r) { mstate[r] = -INFINITY; lstate[r] = 0.f; }

    for (int t = 0; t <= qt; ++t) {
      const int kv0 = t * 64;
      const bool has_next = !(ph == 1 && t == qt);
      if (has_next) {
        const int kvn = (t < qt) ? kv0 + 64 : 0;  // next tile (or phase-1 tile 0)
        const int nb = cur ^ 1;
#pragma unroll
        for (int i = 0; i < 2; ++i) {
          gload_lds16(Ksrc[i] + (size_t)kvn * 1024, &Ks[nb][(w * 64 + i * 256) * 8]);
          gload_lds16(Vsrc[i] + kvn, &Vs[nb][(w * 64 + i * 256) * 8]);
        }
      }
      // ---- QK^T: S[16 q][64 kv] per wave ----
      f32x4 s_acc[4] = {};
#pragma unroll
      for (int ks = 0; ks < 2; ++ks)
#pragma unroll
        for (int kn = 0; kn < 4; ++kn) {
          bf16x8 bf = *(const bf16x8*)&Ks[cur][(kn * 16 + c) * 64 +
                                              (((ks * 4 + g) ^ (c & 7)) * 8)];
          s_acc[kn] =
              __builtin_amdgcn_mfma_f32_16x16x32_bf16(qf[ks], bf, s_acc[kn], 0, 0, 0);
        }
      // ---- scale + causal mask ----
      float s[4][4];
#pragma unroll
      for (int kn = 0; kn < 4; ++kn)
#pragma unroll
        for (int r = 0; r < 4; ++r) s[kn][r] = s_acc[kn][r] * ATT_SCALE;
      if (t == qt) {
#pragma unroll
        for (int kn = 0; kn < 4; ++kn)
#pragma unroll
          for (int r = 0; r < 4; ++r)
            if (kv0 + kn * 16 + c > qt * 64 + w * 16 + g * 4 + r) s[kn][r] = -1e30f;
      }
      // ---- online softmax ----
      float mx[4];
#pragma unroll
      for (int r = 0; r < 4; ++r)
        mx[r] = fmaxf(fmaxf(s[0][r], s[1][r]), fmaxf(s[2][r], s[3][r]));
#pragma unroll
      for (int r = 0; r < 4; ++r) {
        mx[r] = fmaxf(mx[r], __shfl_xor(mx[r], 1));
        mx[r] = fmaxf(mx[r], __shfl_xor(mx[r], 2));
        mx[r] = fmaxf(mx[r], __shfl_xor(mx[r], 4));
        mx[r] = fmaxf(mx[r], __shfl_xor(mx[r], 8));
      }
      float alpha[4];
#pragma unroll
      for (int r = 0; r < 4; ++r) {
        float nm = fmaxf(mstate[r], mx[r]);
        alpha[r] = __expf(mstate[r] - nm);
        mstate[r] = nm;
      }
      float rsum[4] = {0.f, 0.f, 0.f, 0.f};
#pragma unroll
      for (int kn = 0; kn < 4; ++kn)
#pragma unroll
        for (int r = 0; r < 4; ++r) {
          float p = __expf(s[kn][r] - mstate[r]);
          unsigned short pb = f2bf(p);
          rsum[r] += bf2f(pb);
          int q = g * 4 + r, k = kn * 16 + c;
          Plw[q * 64 + (k ^ ((q & 7) << 3))] = pb;
        }
#pragma unroll
      for (int r = 0; r < 4; ++r) {
        rsum[r] += __shfl_xor(rsum[r], 1);
        rsum[r] += __shfl_xor(rsum[r], 2);
        rsum[r] += __shfl_xor(rsum[r], 4);
        rsum[r] += __shfl_xor(rsum[r], 8);
        lstate[r] = lstate[r] * alpha[r] + rsum[r];
      }
#pragma unroll
      for (int dn = 0; dn < 4; ++dn)
#pragma unroll
        for (int r = 0; r < 4; ++r) o_acc[dn][r] *= alpha[r];
      // ---- PV: O[16 q][64 d] += P[16][64] @ V^T ----
      bf16x8 af[2];
#pragma unroll
      for (int ks2 = 0; ks2 < 2; ++ks2)
        af[ks2] = *(const bf16x8*)&Plw[c * 64 + ((ks2 * 32 + g * 8) ^ ((c & 7) << 3))];
#pragma unroll
      for (int ks2 = 0; ks2 < 2; ++ks2)
#pragma unroll
        for (int dn = 0; dn < 4; ++dn) {
          bf16x8 vf = *(const bf16x8*)&Vs[cur][(dn * 16 + c) * 64 +
                                              (((ks2 * 4 + g) ^ (c & 7)) * 8)];
          o_acc[dn] =
              __builtin_amdgcn_mfma_f32_16x16x32_bf16(af[ks2], vf, o_acc[dn], 0, 0, 0);
        }
      __syncthreads();  // drains staging vmcnt + all waves done reading buf[cur]
      if (has_next) cur ^= 1;
    }
    // ---- epilogue for this phase ----
    float inv[4];
#pragma unroll
    for (int r = 0; r < 4; ++r) inv[r] = 1.0f / lstate[r];
#pragma unroll
    for (int dn = 0; dn < 4; ++dn)
#pragma unroll
      for (int r = 0; r < 4; ++r) {
        int row = qt * 64 + w * 16 + g * 4 + r;
        int col = head * HEADD + dn * 16 + c;
        O[(size_t)(b * S_LEN + row) * (NHEADS * HEADD) + col] =
            f2bf(o_acc[dn][r] * inv[r]);
      }
  }
}

extern "C" void kernel_launch(void* const* d_in, const int* in_sizes, int n_in,
                              void* d_out, int out_size, void* d_ws, size_t ws_size,
                              hipStream_t stream) {
  const float* hs = (const float*)d_in[0];
  // d_in[1] = attention_mask: guaranteed causal; implemented analytically
  const float* wq = (const float*)d_in[2];
  const float* wk = (const float*)d_in[3];
  const float* wv = (const float*)d_in[4];
  const float* wo = (const float*)d_in[5];
  float* out = (float*)d_out;

  char* ws = (char*)d_ws;
  unsigned short* hs_bf = (unsigned short*)(ws);                        // 16 MB
  unsigned short* wqT  = (unsigned short*)(ws + ((size_t)16 << 20));    // 8 MB
  unsigned short* wkT  = (unsigned short*)(ws + ((size_t)24 << 20));    // 2 MB (K rows)
  unsigned short* wvT  = (unsigned short*)(ws + ((size_t)26 << 20));    // 2 MB (V rows, contiguous after wkT)
  unsigned short* woT  = (unsigned short*)(ws + ((size_t)28 << 20));    // 8 MB
  unsigned short* Qb   = (unsigned short*)(ws + ((size_t)36 << 20));    // 16 MB
  unsigned short* KVb  = (unsigned short*)(ws + ((size_t)52 << 20));    // 8 MB
  unsigned short* Ab   = (unsigned short*)(ws + ((size_t)60 << 20));    // 16 MB
  unsigned short* VtB  = (unsigned short*)(ws + ((size_t)76 << 20));    // 4 MB

  // 1. hs -> bf16
  int n4 = (B_SZ * S_LEN * HID) / 4;
  cvt_bf16_kernel<<<n4 / 256, 256, 0, stream>>>((const float4*)hs, (ushort4*)hs_bf, n4);

  // 2. weight transposes ([K][N] f32 -> [N][K] bf16)
  dim3 tb(32, 8);
  transpose_cvt_kernel<<<dim3(64, 64), tb, 0, stream>>>(wq, wqT, HID, NHEADS * HEADD);
  transpose_cvt_kernel<<<dim3(16, 64), tb, 0, stream>>>(wk, wkT, HID, NKVH * HEADD);
  transpose_cvt_kernel<<<dim3(16, 64), tb, 0, stream>>>(wv, wvT, HID, NKVH * HEADD);
  transpose_cvt_kernel<<<dim3(64, 64), tb, 0, stream>>>(wo, woT, NHEADS * HEADD, HID);

  // 3. projections: Q (N=2048) and merged KV (N=1024; wkT||wvT contiguous)
  gemm_bt_kernel<unsigned short><<<dim3(16, 32), 256, 0, stream>>>(
      hs_bf, wqT, Qb, B_SZ * S_LEN, NHEADS * HEADD, HID);
  gemm_bt_kernel<unsigned short><<<dim3(8, 32), 256, 0, stream>>>(
      hs_bf, wkT, KVb, B_SZ * S_LEN, 1024, HID);

  // 3b. V -> V^T
  transpose_v_kernel<<<dim3(S_LEN / 32, HEADD / 32, B_SZ * NKVH), tb, 0, stream>>>(
      KVb, VtB);

  // 4. attention (MFMA flash, paired + dbuf via global_load_lds)
  mfma_attn_kernel<<<dim3(S_LEN / 128, NHEADS, B_SZ), 256, 0, stream>>>(
      Qb, KVb, VtB, Ab);

  // 5. output projection (fp32 out)
  gemm_bt_kernel<float><<<dim3(16, 32), 256, 0, stream>>>(
      Ab, woT, out, B_SZ * S_LEN, HID, HID);
}

// Round 6
// 278.830 us; speedup vs baseline: 1.3616x; 1.1326x over previous
//
#include <hip/hip_runtime.h>
#include <hip/hip_bf16.h>
#include <type_traits>

// GroupedQueryAttention: B=2, S=2048, H=2048, NH=32, NKV=8, HD=64, G=4
// Pipeline:
//   1. hs -> bf16
//   2. transpose+cvt weights to [N][K] bf16 (wq scaled by 0.125*log2e)
//   3. Q = hs@wq (N=2048), KV = hs@[wk|wv] (N=1024, merged)   [BK=64 GEMM]
//   3b. V -> V^T  ([b][kvh][d][s]) for MFMA PV step
//   4. MFMA flash attention: causal-paired q-tiles, dbuf K/V via global_load_lds,
//      exp2-domain softmax with defer-max (T13)
//   5. out = attn@wo (fp32 out)

#define B_SZ 2
#define S_LEN 2048
#define HID 2048
#define NHEADS 32
#define NKVH 8
#define HEADD 64
// 0.125 * log2(e): QK^T then directly exp2()
#define QK_SCALE 0.18033688f

typedef __attribute__((ext_vector_type(8))) short bf16x8;
typedef __attribute__((ext_vector_type(4))) float f32x4;

__device__ __forceinline__ float bf2f(unsigned short u) {
  union { unsigned int i; float f; } v;
  v.i = ((unsigned int)u) << 16;
  return v.f;
}
__device__ __forceinline__ unsigned short f2bf(float f) {
  union { float f; unsigned int i; } v;
  v.f = f;
  unsigned int r = v.i + 0x7fffu + ((v.i >> 16) & 1u);
  return (unsigned short)(r >> 16);
}
__device__ __forceinline__ unsigned short f2bf_rn(float f) {
  union { __hip_bfloat16 h; unsigned short u; } cv;
  cv.h = __float2bfloat16(f);
  return cv.u;
}
#if __has_builtin(__builtin_amdgcn_exp2f)
__device__ __forceinline__ float exp2v(float x) { return __builtin_amdgcn_exp2f(x); }
#else
__device__ __forceinline__ float exp2v(float x) { return exp2f(x); }
#endif
// async global->LDS, 16B per lane; lds dest = wave-uniform base + lane*16
__device__ __forceinline__ void gload_lds16(const unsigned short* g, unsigned short* l) {
  __builtin_amdgcn_global_load_lds(
      (const __attribute__((address_space(1))) unsigned int*)g,
      (__attribute__((address_space(3))) unsigned int*)l, 16, 0, 0);
}

// ---------------- elementwise f32 -> bf16 ----------------
__global__ void cvt_bf16_kernel(const float4* __restrict__ in,
                                ushort4* __restrict__ out, int n4) {
  int i = blockIdx.x * blockDim.x + threadIdx.x;
  if (i >= n4) return;
  float4 v = in[i];
  ushort4 o;
  o.x = f2bf(v.x); o.y = f2bf(v.y); o.z = f2bf(v.z); o.w = f2bf(v.w);
  out[i] = o;
}

// ---------------- transpose + cvt + scale: in[R][C] f32 -> out[C][R] bf16 ----
__global__ void transpose_cvt_kernel(const float* __restrict__ in,
                                     unsigned short* __restrict__ out,
                                     int R, int C, float scale) {
  __shared__ float tile[32][33];
  int c0 = blockIdx.x * 32, r0 = blockIdx.y * 32;
  int x = threadIdx.x, y = threadIdx.y;
#pragma unroll
  for (int i = 0; i < 32; i += 8)
    tile[y + i][x] = in[(size_t)(r0 + y + i) * C + c0 + x];
  __syncthreads();
#pragma unroll
  for (int i = 0; i < 32; i += 8)
    out[(size_t)(c0 + y + i) * R + r0 + x] = f2bf(tile[x][y + i] * scale);
}

// ---------------- bf16 transpose: KV[b,s,512+kvh*64+d] -> Vt[(b*8+kvh)*64+d][s] ----
__global__ void transpose_v_kernel(const unsigned short* __restrict__ KVb,
                                   unsigned short* __restrict__ Vt) {
  __shared__ unsigned short tile[32][33];
  int s0 = blockIdx.x * 32, d0 = blockIdx.y * 32;
  int bk = blockIdx.z;
  int b = bk >> 3, kvh = bk & 7;
  int x = threadIdx.x, y = threadIdx.y;
#pragma unroll
  for (int i = 0; i < 32; i += 8)
    tile[y + i][x] =
        KVb[(size_t)(b * S_LEN + s0 + y + i) * 1024 + 512 + kvh * HEADD + d0 + x];
  __syncthreads();
#pragma unroll
  for (int i = 0; i < 32; i += 8)
    Vt[((size_t)(b * NKVH + kvh) * HEADD + d0 + y + i) * S_LEN + s0 + x] =
        tile[x][y + i];
}

// ---------------- bf16 MFMA GEMM: C[M][N] = A[M][K] * Bt[N][K]^T ----------------
// 128x128 tile, BK=64, 4 waves; global_load_lds staging with pre-swizzled source
// (slot ^= row&7) so stride-128B fragment reads are ~2-way (free) bank aliased.
template <typename OutT>
__global__ __launch_bounds__(256) void gemm_bt_kernel(
    const unsigned short* __restrict__ A, const unsigned short* __restrict__ Bt,
    OutT* __restrict__ C, int M, int N, int K) {
  __shared__ unsigned short ldsA[128 * 64];
  __shared__ unsigned short ldsB[128 * 64];
  const int tid = threadIdx.x;
  const int wave = tid >> 6;
  const int lane = tid & 63;
  const int m0 = blockIdx.y * 128;
  const int n0 = blockIdx.x * 128;
  const int wr = wave >> 1, wc = wave & 1;
  f32x4 acc[4][4] = {};

  // staging chunk c = tid + i*256: row=c>>3, slot=c&7; src k pre-swizzled
  size_t offA[4], offB[4];
#pragma unroll
  for (int i = 0; i < 4; ++i) {
    int cc = tid + i * 256;
    int row = cc >> 3, slot = cc & 7;
    int xk = (slot ^ (row & 7)) * 8;
    offA[i] = (size_t)(m0 + row) * K + xk;
    offB[i] = (size_t)(n0 + row) * K + xk;
  }
  const int rl = lane & 15, g = lane >> 4;

  for (int k0 = 0; k0 < K; k0 += 64) {
    __syncthreads();  // all waves done reading previous tile
#pragma unroll
    for (int i = 0; i < 4; ++i) {
      gload_lds16(A + offA[i] + k0, &ldsA[(wave * 64 + i * 256) * 8]);
      gload_lds16(Bt + offB[i] + k0, &ldsB[(wave * 64 + i * 256) * 8]);
    }
    __syncthreads();  // compiler drains vmcnt before this barrier
    bf16x8 a[2][4], b[2][4];
#pragma unroll
    for (int ks = 0; ks < 2; ++ks) {
      const int xs = ((ks * 4 + g) ^ (rl & 7)) * 8;
#pragma unroll
      for (int mi = 0; mi < 4; ++mi)
        a[ks][mi] = *(const bf16x8*)&ldsA[(wr * 64 + mi * 16 + rl) * 64 + xs];
#pragma unroll
      for (int ni = 0; ni < 4; ++ni)
        b[ks][ni] = *(const bf16x8*)&ldsB[(wc * 64 + ni * 16 + rl) * 64 + xs];
    }
#pragma unroll
    for (int ks = 0; ks < 2; ++ks)
#pragma unroll
      for (int mi = 0; mi < 4; ++mi)
#pragma unroll
        for (int ni = 0; ni < 4; ++ni)
          acc[mi][ni] = __builtin_amdgcn_mfma_f32_16x16x32_bf16(a[ks][mi], b[ks][ni],
                                                                acc[mi][ni], 0, 0, 0);
  }
#pragma unroll
  for (int mi = 0; mi < 4; ++mi)
#pragma unroll
    for (int ni = 0; ni < 4; ++ni)
#pragma unroll
      for (int r = 0; r < 4; ++r) {
        int row = m0 + wr * 64 + mi * 16 + (lane >> 4) * 4 + r;
        int col = n0 + wc * 64 + ni * 16 + (lane & 15);
        float v = acc[mi][ni][r];
        if constexpr (std::is_same_v<OutT, unsigned short>)
          C[(size_t)row * N + col] = f2bf(v);
        else
          C[(size_t)row * N + col] = v;
      }
}

// ---------------- MFMA flash attention ----------------
// grid: (16 pairs, NH, B). block 256 = 4 waves; wave w owns 16 q-rows.
// Q pre-scaled by 0.125*log2e => scores are exp2-domain. Defer-max (T13, THR=8).
__global__ __launch_bounds__(256) void mfma_attn_kernel(
    const unsigned short* __restrict__ Q,    // [B*S][NH*64] (pre-scaled)
    const unsigned short* __restrict__ KVb,  // [B*S][1024]; K at col kvh*64
    const unsigned short* __restrict__ Vt,   // [(b*8+kvh)*64+d][S]
    unsigned short* __restrict__ O) {        // [B*S][NH*64]
  __shared__ unsigned short Ks[2][64 * 64];
  __shared__ unsigned short Vs[2][64 * 64];
  __shared__ unsigned short Pl[4 * 16 * 64];
  const int head = blockIdx.y, b = blockIdx.z;
  const int kvh = head >> 2;
  const int tid = threadIdx.x;
  const int w = tid >> 6, lane = tid & 63;
  const int c = lane & 15, g = lane >> 4;
  unsigned short* Plw = Pl + w * 1024;
  const int srow = tid >> 3, sslot = tid & 7;
  const int xslot = sslot ^ (srow & 7);

  // pre-swizzled per-lane global sources; LDS dest stays linear
  const unsigned short* Ksrc[2];
  const unsigned short* Vsrc[2];
#pragma unroll
  for (int i = 0; i < 2; ++i) {
    int row = srow + i * 32;
    Ksrc[i] = KVb + (size_t)(b * S_LEN + row) * 1024 + kvh * HEADD + xslot * 8;
    Vsrc[i] = Vt + ((size_t)(b * NKVH + kvh) * HEADD + row) * S_LEN + xslot * 8;
  }

  // prologue: stage tile 0 into buf 0
#pragma unroll
  for (int i = 0; i < 2; ++i) {
    gload_lds16(Ksrc[i], &Ks[0][(w * 64 + i * 256) * 8]);
    gload_lds16(Vsrc[i], &Vs[0][(w * 64 + i * 256) * 8]);
  }
  __syncthreads();
  int cur = 0;

  for (int ph = 0; ph < 2; ++ph) {
    const int qt = (ph == 0) ? (int)blockIdx.x : (S_LEN / 64 - 1) - (int)blockIdx.x;
    bf16x8 qf[2];
    {
      const unsigned short* qp =
          Q + (size_t)(b * S_LEN + qt * 64 + w * 16 + c) * (NHEADS * HEADD) +
          head * HEADD + g * 8;
      qf[0] = *(const bf16x8*)(qp);
      qf[1] = *(const bf16x8*)(qp + 32);
    }
    f32x4 o_acc[4] = {};
    float mstate[4], lstate[4];
#pragma unroll
    for (int r = 0; r < 4; ++r) { mstate[r] = -INFINITY; lstate[r] = 0.f; }

    for (int t = 0; t <= qt; ++t) {
      const int kv0 = t * 64;
      const bool has_next = !(ph == 1 && t == qt);
      if (has_next) {
        const int kvn = (t < qt) ? kv0 + 64 : 0;  // next tile (or phase-1 tile 0)
        const int nb = cur ^ 1;
#pragma unroll
        for (int i = 0; i < 2; ++i) {
          gload_lds16(Ksrc[i] + (size_t)kvn * 1024, &Ks[nb][(w * 64 + i * 256) * 8]);
          gload_lds16(Vsrc[i] + kvn, &Vs[nb][(w * 64 + i * 256) * 8]);
        }
      }
      // ---- QK^T: S[16 q][64 kv] per wave (exp2 domain) ----
      f32x4 s_acc[4] = {};
#pragma unroll
      for (int ks = 0; ks < 2; ++ks)
#pragma unroll
        for (int kn = 0; kn < 4; ++kn) {
          bf16x8 bf = *(const bf16x8*)&Ks[cur][(kn * 16 + c) * 64 +
                                              (((ks * 4 + g) ^ (c & 7)) * 8)];
          s_acc[kn] =
              __builtin_amdgcn_mfma_f32_16x16x32_bf16(qf[ks], bf, s_acc[kn], 0, 0, 0);
        }
      // ---- causal mask ----
      float s[4][4];
#pragma unroll
      for (int kn = 0; kn < 4; ++kn)
#pragma unroll
        for (int r = 0; r < 4; ++r) s[kn][r] = s_acc[kn][r];
      if (t == qt) {
#pragma unroll
        for (int kn = 0; kn < 4; ++kn)
#pragma unroll
          for (int r = 0; r < 4; ++r)
            if (kv0 + kn * 16 + c > qt * 64 + w * 16 + g * 4 + r) s[kn][r] = -1e30f;
      }
      // ---- online softmax, defer-max (T13) ----
      float mx[4];
#pragma unroll
      for (int r = 0; r < 4; ++r)
        mx[r] = fmaxf(fmaxf(s[0][r], s[1][r]), fmaxf(s[2][r], s[3][r]));
#pragma unroll
      for (int r = 0; r < 4; ++r) {
        mx[r] = fmaxf(mx[r], __shfl_xor(mx[r], 1));
        mx[r] = fmaxf(mx[r], __shfl_xor(mx[r], 2));
        mx[r] = fmaxf(mx[r], __shfl_xor(mx[r], 4));
        mx[r] = fmaxf(mx[r], __shfl_xor(mx[r], 8));
      }
      bool grow = (mx[0] > mstate[0] + 8.f) || (mx[1] > mstate[1] + 8.f) ||
                  (mx[2] > mstate[2] + 8.f) || (mx[3] > mstate[3] + 8.f);
      if (__any(grow)) {
#pragma unroll
        for (int r = 0; r < 4; ++r) {
          float nm = fmaxf(mstate[r], mx[r]);
          float al = exp2v(mstate[r] - nm);
          mstate[r] = nm;
          lstate[r] *= al;
#pragma unroll
          for (int dn = 0; dn < 4; ++dn) o_acc[dn][r] *= al;
        }
      }
      float rsum[4] = {0.f, 0.f, 0.f, 0.f};
#pragma unroll
      for (int kn = 0; kn < 4; ++kn)
#pragma unroll
        for (int r = 0; r < 4; ++r) {
          float p = exp2v(s[kn][r] - mstate[r]);
          rsum[r] += p;
          int q = g * 4 + r, k = kn * 16 + c;
          Plw[q * 64 + (k ^ ((q & 7) << 3))] = f2bf_rn(p);
        }
#pragma unroll
      for (int r = 0; r < 4; ++r) {
        rsum[r] += __shfl_xor(rsum[r], 1);
        rsum[r] += __shfl_xor(rsum[r], 2);
        rsum[r] += __shfl_xor(rsum[r], 4);
        rsum[r] += __shfl_xor(rsum[r], 8);
        lstate[r] += rsum[r];
      }
      // ---- PV: O[16 q][64 d] += P[16][64] @ V^T ----
      bf16x8 af[2];
#pragma unroll
      for (int ks2 = 0; ks2 < 2; ++ks2)
        af[ks2] = *(const bf16x8*)&Plw[c * 64 + ((ks2 * 32 + g * 8) ^ ((c & 7) << 3))];
#pragma unroll
      for (int ks2 = 0; ks2 < 2; ++ks2)
#pragma unroll
        for (int dn = 0; dn < 4; ++dn) {
          bf16x8 vf = *(const bf16x8*)&Vs[cur][(dn * 16 + c) * 64 +
                                              (((ks2 * 4 + g) ^ (c & 7)) * 8)];
          o_acc[dn] =
              __builtin_amdgcn_mfma_f32_16x16x32_bf16(af[ks2], vf, o_acc[dn], 0, 0, 0);
        }
      __syncthreads();  // drains staging vmcnt + all waves done reading buf[cur]
      if (has_next) cur ^= 1;
    }
    // ---- epilogue for this phase ----
    float inv[4];
#pragma unroll
    for (int r = 0; r < 4; ++r) inv[r] = 1.0f / lstate[r];
#pragma unroll
    for (int dn = 0; dn < 4; ++dn)
#pragma unroll
      for (int r = 0; r < 4; ++r) {
        int row = qt * 64 + w * 16 + g * 4 + r;
        int col = head * HEADD + dn * 16 + c;
        O[(size_t)(b * S_LEN + row) * (NHEADS * HEADD) + col] =
            f2bf(o_acc[dn][r] * inv[r]);
      }
  }
}

extern "C" void kernel_launch(void* const* d_in, const int* in_sizes, int n_in,
                              void* d_out, int out_size, void* d_ws, size_t ws_size,
                              hipStream_t stream) {
  const float* hs = (const float*)d_in[0];
  // d_in[1] = attention_mask: guaranteed causal; implemented analytically
  const float* wq = (const float*)d_in[2];
  const float* wk = (const float*)d_in[3];
  const float* wv = (const float*)d_in[4];
  const float* wo = (const float*)d_in[5];
  float* out = (float*)d_out;

  char* ws = (char*)d_ws;
  unsigned short* hs_bf = (unsigned short*)(ws);                        // 16 MB
  unsigned short* wqT  = (unsigned short*)(ws + ((size_t)16 << 20));    // 8 MB
  unsigned short* wkT  = (unsigned short*)(ws + ((size_t)24 << 20));    // 2 MB (K rows)
  unsigned short* wvT  = (unsigned short*)(ws + ((size_t)26 << 20));    // 2 MB (V rows, contiguous after wkT)
  unsigned short* woT  = (unsigned short*)(ws + ((size_t)28 << 20));    // 8 MB
  unsigned short* Qb   = (unsigned short*)(ws + ((size_t)36 << 20));    // 16 MB
  unsigned short* KVb  = (unsigned short*)(ws + ((size_t)52 << 20));    // 8 MB
  unsigned short* Ab   = (unsigned short*)(ws + ((size_t)60 << 20));    // 16 MB
  unsigned short* VtB  = (unsigned short*)(ws + ((size_t)76 << 20));    // 4 MB

  // 1. hs -> bf16
  int n4 = (B_SZ * S_LEN * HID) / 4;
  cvt_bf16_kernel<<<n4 / 256, 256, 0, stream>>>((const float4*)hs, (ushort4*)hs_bf, n4);

  // 2. weight transposes ([K][N] f32 -> [N][K] bf16); wq gets exp2-domain scale
  dim3 tb(32, 8);
  transpose_cvt_kernel<<<dim3(64, 64), tb, 0, stream>>>(wq, wqT, HID, NHEADS * HEADD,
                                                        QK_SCALE);
  transpose_cvt_kernel<<<dim3(16, 64), tb, 0, stream>>>(wk, wkT, HID, NKVH * HEADD,
                                                        1.0f);
  transpose_cvt_kernel<<<dim3(16, 64), tb, 0, stream>>>(wv, wvT, HID, NKVH * HEADD,
                                                        1.0f);
  transpose_cvt_kernel<<<dim3(64, 64), tb, 0, stream>>>(wo, woT, NHEADS * HEADD, HID,
                                                        1.0f);

  // 3. projections: Q (N=2048) and merged KV (N=1024; wkT||wvT contiguous)
  gemm_bt_kernel<unsigned short><<<dim3(16, 32), 256, 0, stream>>>(
      hs_bf, wqT, Qb, B_SZ * S_LEN, NHEADS * HEADD, HID);
  gemm_bt_kernel<unsigned short><<<dim3(8, 32), 256, 0, stream>>>(
      hs_bf, wkT, KVb, B_SZ * S_LEN, 1024, HID);

  // 3b. V -> V^T
  transpose_v_kernel<<<dim3(S_LEN / 32, HEADD / 32, B_SZ * NKVH), tb, 0, stream>>>(
      KVb, VtB);

  // 4. attention (MFMA flash, paired + dbuf via global_load_lds)
  mfma_attn_kernel<<<dim3(S_LEN / 128, NHEADS, B_SZ), 256, 0, stream>>>(
      Qb, KVb, VtB, Ab);

  // 5. output projection (fp32 out)
  gemm_bt_kernel<float><<<dim3(16, 32), 256, 0, stream>>>(
      Ab, woT, out, B_SZ * S_LEN, HID, HID);
}

// Round 7
// 221.837 us; speedup vs baseline: 1.7115x; 1.2569x over previous
//
#include <hip/hip_runtime.h>
#include <hip/hip_bf16.h>
#include <type_traits>

// GroupedQueryAttention: B=2, S=2048, H=2048, NH=32, NKV=8, HD=64, G=4
// Pipeline:
//   1. hs -> bf16
//   2. transpose+cvt weights to [N][K] bf16 (wq scaled by 0.125*log2e)
//   3. Q = hs@wq (N=2048), KV = hs@[wk|wv] (N=1024, merged)   [BK=64 GEMM]
//   3b. V -> V^T  ([b][kvh][d][s]) for MFMA PV step
//   4. MFMA flash attention: swapped QK^T (S^T[kv][q]) -> lane-local softmax,
//      causal-paired q-tiles, dbuf K/V via global_load_lds, defer-max (T13)
//   5. out = attn@wo (fp32 out)

#define B_SZ 2
#define S_LEN 2048
#define HID 2048
#define NHEADS 32
#define NKVH 8
#define HEADD 64
// 0.125 * log2(e): QK^T then directly exp2()
#define QK_SCALE 0.18033688f

typedef __attribute__((ext_vector_type(8))) short bf16x8;
typedef __attribute__((ext_vector_type(4))) float f32x4;

__device__ __forceinline__ float bf2f(unsigned short u) {
  union { unsigned int i; float f; } v;
  v.i = ((unsigned int)u) << 16;
  return v.f;
}
__device__ __forceinline__ unsigned short f2bf(float f) {
  union { float f; unsigned int i; } v;
  v.f = f;
  unsigned int r = v.i + 0x7fffu + ((v.i >> 16) & 1u);
  return (unsigned short)(r >> 16);
}
__device__ __forceinline__ unsigned short f2bf_rn(float f) {
  union { __hip_bfloat16 h; unsigned short u; } cv;
  cv.h = __float2bfloat16(f);
  return cv.u;
}
#if __has_builtin(__builtin_amdgcn_exp2f)
__device__ __forceinline__ float exp2v(float x) { return __builtin_amdgcn_exp2f(x); }
#else
__device__ __forceinline__ float exp2v(float x) { return exp2f(x); }
#endif
// async global->LDS, 16B per lane; lds dest = wave-uniform base + lane*16
__device__ __forceinline__ void gload_lds16(const unsigned short* g, unsigned short* l) {
  __builtin_amdgcn_global_load_lds(
      (const __attribute__((address_space(1))) unsigned int*)g,
      (__attribute__((address_space(3))) unsigned int*)l, 16, 0, 0);
}

// ---------------- elementwise f32 -> bf16 ----------------
__global__ void cvt_bf16_kernel(const float4* __restrict__ in,
                                ushort4* __restrict__ out, int n4) {
  int i = blockIdx.x * blockDim.x + threadIdx.x;
  if (i >= n4) return;
  float4 v = in[i];
  ushort4 o;
  o.x = f2bf(v.x); o.y = f2bf(v.y); o.z = f2bf(v.z); o.w = f2bf(v.w);
  out[i] = o;
}

// ---------------- transpose + cvt + scale: in[R][C] f32 -> out[C][R] bf16 ----
__global__ void transpose_cvt_kernel(const float* __restrict__ in,
                                     unsigned short* __restrict__ out,
                                     int R, int C, float scale) {
  __shared__ float tile[32][33];
  int c0 = blockIdx.x * 32, r0 = blockIdx.y * 32;
  int x = threadIdx.x, y = threadIdx.y;
#pragma unroll
  for (int i = 0; i < 32; i += 8)
    tile[y + i][x] = in[(size_t)(r0 + y + i) * C + c0 + x];
  __syncthreads();
#pragma unroll
  for (int i = 0; i < 32; i += 8)
    out[(size_t)(c0 + y + i) * R + r0 + x] = f2bf(tile[x][y + i] * scale);
}

// ---------------- bf16 transpose: KV[b,s,512+kvh*64+d] -> Vt[(b*8+kvh)*64+d][s] ----
__global__ void transpose_v_kernel(const unsigned short* __restrict__ KVb,
                                   unsigned short* __restrict__ Vt) {
  __shared__ unsigned short tile[32][33];
  int s0 = blockIdx.x * 32, d0 = blockIdx.y * 32;
  int bk = blockIdx.z;
  int b = bk >> 3, kvh = bk & 7;
  int x = threadIdx.x, y = threadIdx.y;
#pragma unroll
  for (int i = 0; i < 32; i += 8)
    tile[y + i][x] =
        KVb[(size_t)(b * S_LEN + s0 + y + i) * 1024 + 512 + kvh * HEADD + d0 + x];
  __syncthreads();
#pragma unroll
  for (int i = 0; i < 32; i += 8)
    Vt[((size_t)(b * NKVH + kvh) * HEADD + d0 + y + i) * S_LEN + s0 + x] =
        tile[x][y + i];
}

// ---------------- bf16 MFMA GEMM: C[M][N] = A[M][K] * Bt[N][K]^T ----------------
// 128x128 tile, BK=64, 4 waves; global_load_lds staging with pre-swizzled source.
// 1-D grid with XCD-aware swizzle (T1): consecutive same-XCD blocks share A panel.
template <typename OutT>
__global__ __launch_bounds__(256) void gemm_bt_kernel(
    const unsigned short* __restrict__ A, const unsigned short* __restrict__ Bt,
    OutT* __restrict__ C, int M, int N, int K) {
  __shared__ unsigned short ldsA[128 * 64];
  __shared__ unsigned short ldsB[128 * 64];
  const int tid = threadIdx.x;
  const int wave = tid >> 6;
  const int lane = tid & 63;
  // XCD swizzle: nwg % 8 == 0 for all our launches (512 / 256 / 512)
  const int nwg = gridDim.x;
  const int orig = blockIdx.x;
  const int swz = (orig & 7) * (nwg >> 3) + (orig >> 3);
  const int ntn = N >> 7;
  const int lntn = 31 - __clz(ntn);  // ntn is a power of two (16 or 8)
  const int m0 = (swz >> lntn) << 7;
  const int n0 = (swz & (ntn - 1)) << 7;
  const int wr = wave >> 1, wc = wave & 1;
  f32x4 acc[4][4] = {};

  // staging chunk c = tid + i*256: row=c>>3, slot=c&7; src k pre-swizzled
  size_t offA[4], offB[4];
#pragma unroll
  for (int i = 0; i < 4; ++i) {
    int cc = tid + i * 256;
    int row = cc >> 3, slot = cc & 7;
    int xk = (slot ^ (row & 7)) * 8;
    offA[i] = (size_t)(m0 + row) * K + xk;
    offB[i] = (size_t)(n0 + row) * K + xk;
  }
  const int rl = lane & 15, g = lane >> 4;

  for (int k0 = 0; k0 < K; k0 += 64) {
    __syncthreads();  // all waves done reading previous tile
#pragma unroll
    for (int i = 0; i < 4; ++i) {
      gload_lds16(A + offA[i] + k0, &ldsA[(wave * 64 + i * 256) * 8]);
      gload_lds16(Bt + offB[i] + k0, &ldsB[(wave * 64 + i * 256) * 8]);
    }
    __syncthreads();  // compiler drains vmcnt before this barrier
    bf16x8 a[2][4], b[2][4];
#pragma unroll
    for (int ks = 0; ks < 2; ++ks) {
      const int xs = ((ks * 4 + g) ^ (rl & 7)) * 8;
#pragma unroll
      for (int mi = 0; mi < 4; ++mi)
        a[ks][mi] = *(const bf16x8*)&ldsA[(wr * 64 + mi * 16 + rl) * 64 + xs];
#pragma unroll
      for (int ni = 0; ni < 4; ++ni)
        b[ks][ni] = *(const bf16x8*)&ldsB[(wc * 64 + ni * 16 + rl) * 64 + xs];
    }
#pragma unroll
    for (int ks = 0; ks < 2; ++ks)
#pragma unroll
      for (int mi = 0; mi < 4; ++mi)
#pragma unroll
        for (int ni = 0; ni < 4; ++ni)
          acc[mi][ni] = __builtin_amdgcn_mfma_f32_16x16x32_bf16(a[ks][mi], b[ks][ni],
                                                                acc[mi][ni], 0, 0, 0);
  }
#pragma unroll
  for (int mi = 0; mi < 4; ++mi)
#pragma unroll
    for (int ni = 0; ni < 4; ++ni)
#pragma unroll
      for (int r = 0; r < 4; ++r) {
        int row = m0 + wr * 64 + mi * 16 + (lane >> 4) * 4 + r;
        int col = n0 + wc * 64 + ni * 16 + (lane & 15);
        float v = acc[mi][ni][r];
        if constexpr (std::is_same_v<OutT, unsigned short>)
          C[(size_t)row * N + col] = f2bf(v);
        else
          C[(size_t)row * N + col] = v;
      }
}

// ---------------- MFMA flash attention (swapped QK^T, lane-local softmax) ------
// grid: (16 pairs, NH, B). block 256 = 4 waves; wave w owns 16 q-rows.
// QK^T computed as mfma(K, Q) -> S^T[kv][q]: lane (g,c) holds q=c,
// kv = kn*16 + g*4 + r. Row softmax = in-lane tree + shfl_xor(16/32).
__global__ __launch_bounds__(256) void mfma_attn_kernel(
    const unsigned short* __restrict__ Q,    // [B*S][NH*64] (pre-scaled)
    const unsigned short* __restrict__ KVb,  // [B*S][1024]; K at col kvh*64
    const unsigned short* __restrict__ Vt,   // [(b*8+kvh)*64+d][S]
    unsigned short* __restrict__ O) {        // [B*S][NH*64]
  __shared__ unsigned short Ks[2][64 * 64];
  __shared__ unsigned short Vs[2][64 * 64];
  __shared__ unsigned short Pl[4 * 16 * 64];
  const int head = blockIdx.y, b = blockIdx.z;
  const int kvh = head >> 2;
  const int tid = threadIdx.x;
  const int w = tid >> 6, lane = tid & 63;
  const int c = lane & 15, g = lane >> 4;
  unsigned short* Plw = Pl + w * 1024;
  const int srow = tid >> 3, sslot = tid & 7;
  const int xslot = sslot ^ (srow & 7);

  // pre-swizzled per-lane global sources; LDS dest stays linear
  const unsigned short* Ksrc[2];
  const unsigned short* Vsrc[2];
#pragma unroll
  for (int i = 0; i < 2; ++i) {
    int row = srow + i * 32;
    Ksrc[i] = KVb + (size_t)(b * S_LEN + row) * 1024 + kvh * HEADD + xslot * 8;
    Vsrc[i] = Vt + ((size_t)(b * NKVH + kvh) * HEADD + row) * S_LEN + xslot * 8;
  }

  // prologue: stage tile 0 into buf 0
#pragma unroll
  for (int i = 0; i < 2; ++i) {
    gload_lds16(Ksrc[i], &Ks[0][(w * 64 + i * 256) * 8]);
    gload_lds16(Vsrc[i], &Vs[0][(w * 64 + i * 256) * 8]);
  }
  __syncthreads();
  int cur = 0;

  for (int ph = 0; ph < 2; ++ph) {
    const int qt = (ph == 0) ? (int)blockIdx.x : (S_LEN / 64 - 1) - (int)blockIdx.x;
    bf16x8 qf[2];
    {
      const unsigned short* qp =
          Q + (size_t)(b * S_LEN + qt * 64 + w * 16 + c) * (NHEADS * HEADD) +
          head * HEADD + g * 8;
      qf[0] = *(const bf16x8*)(qp);
      qf[1] = *(const bf16x8*)(qp + 32);
    }
    f32x4 o_acc[4] = {};       // O rows q = g*4+r, col d = dn*16+c
    float mstate = -INFINITY;  // per-lane: q-row c
    float lstate = 0.f;

    for (int t = 0; t <= qt; ++t) {
      const int kv0 = t * 64;
      const bool has_next = !(ph == 1 && t == qt);
      if (has_next) {
        const int kvn = (t < qt) ? kv0 + 64 : 0;  // next tile (or phase-1 tile 0)
        const int nb = cur ^ 1;
#pragma unroll
        for (int i = 0; i < 2; ++i) {
          gload_lds16(Ksrc[i] + (size_t)kvn * 1024, &Ks[nb][(w * 64 + i * 256) * 8]);
          gload_lds16(Vsrc[i] + kvn, &Vs[nb][(w * 64 + i * 256) * 8]);
        }
      }
      // ---- swapped QK^T: S^T[64 kv][16 q]; lane (g,c): q=c, kv=kn*16+g*4+r ----
      f32x4 s_acc[4] = {};
#pragma unroll
      for (int ks = 0; ks < 2; ++ks)
#pragma unroll
        for (int kn = 0; kn < 4; ++kn) {
          bf16x8 kf = *(const bf16x8*)&Ks[cur][(kn * 16 + c) * 64 +
                                              (((ks * 4 + g) ^ (c & 7)) * 8)];
          s_acc[kn] =
              __builtin_amdgcn_mfma_f32_16x16x32_bf16(kf, qf[ks], s_acc[kn], 0, 0, 0);
        }
      // ---- causal mask (lane-local) ----
      if (t == qt) {
        const int qg = qt * 64 + w * 16 + c;
#pragma unroll
        for (int kn = 0; kn < 4; ++kn)
#pragma unroll
          for (int r = 0; r < 4; ++r)
            if (kv0 + kn * 16 + g * 4 + r > qg) s_acc[kn][r] = -1e30f;
      }
      // ---- row max: in-lane tree + 2 shuffles ----
      float mk[4];
#pragma unroll
      for (int kn = 0; kn < 4; ++kn)
        mk[kn] = fmaxf(fmaxf(s_acc[kn][0], s_acc[kn][1]),
                       fmaxf(s_acc[kn][2], s_acc[kn][3]));
      float mx = fmaxf(fmaxf(mk[0], mk[1]), fmaxf(mk[2], mk[3]));
      mx = fmaxf(mx, __shfl_xor(mx, 16));
      mx = fmaxf(mx, __shfl_xor(mx, 32));
      // ---- defer-max (T13): rescale only when max grew past threshold ----
      if (__any(mx > mstate + 8.f)) {
        float nm = fmaxf(mstate, mx);
        float al = exp2v(mstate - nm);
        mstate = nm;
        lstate *= al;
        float alr[4];
#pragma unroll
        for (int r = 0; r < 4; ++r) alr[r] = __shfl(al, g * 4 + r);
#pragma unroll
        for (int dn = 0; dn < 4; ++dn)
#pragma unroll
          for (int r = 0; r < 4; ++r) o_acc[dn][r] *= alr[r];
      }
      // ---- P = exp2(s - m): in-lane, pack 4 bf16 per 8B LDS write ----
      float rs = 0.f;
#pragma unroll
      for (int kn = 0; kn < 4; ++kn) {
        union { unsigned short u[4]; uint2 v; } pk;
#pragma unroll
        for (int r = 0; r < 4; ++r) {
          float p = exp2v(s_acc[kn][r] - mstate);
          rs += p;
          pk.u[r] = f2bf_rn(p);
        }
        *(uint2*)&Plw[c * 64 + ((kn * 16 + g * 4) ^ ((c & 7) << 3))] = pk.v;
      }
      rs += __shfl_xor(rs, 16);
      rs += __shfl_xor(rs, 32);
      lstate += rs;
      // ---- PV: O[16 q][64 d] += P[16][64] @ V^T ----
      bf16x8 af[2];
#pragma unroll
      for (int ks2 = 0; ks2 < 2; ++ks2)
        af[ks2] = *(const bf16x8*)&Plw[c * 64 + ((ks2 * 32 + g * 8) ^ ((c & 7) << 3))];
#pragma unroll
      for (int ks2 = 0; ks2 < 2; ++ks2)
#pragma unroll
        for (int dn = 0; dn < 4; ++dn) {
          bf16x8 vf = *(const bf16x8*)&Vs[cur][(dn * 16 + c) * 64 +
                                              (((ks2 * 4 + g) ^ (c & 7)) * 8)];
          o_acc[dn] =
              __builtin_amdgcn_mfma_f32_16x16x32_bf16(af[ks2], vf, o_acc[dn], 0, 0, 0);
        }
      __syncthreads();  // drains staging vmcnt + all waves done reading buf[cur]
      if (has_next) cur ^= 1;
    }
    // ---- epilogue for this phase ----
    float inv = 1.0f / lstate;
    float invr[4];
#pragma unroll
    for (int r = 0; r < 4; ++r) invr[r] = __shfl(inv, g * 4 + r);
#pragma unroll
    for (int dn = 0; dn < 4; ++dn)
#pragma unroll
      for (int r = 0; r < 4; ++r) {
        int row = qt * 64 + w * 16 + g * 4 + r;
        int col = head * HEADD + dn * 16 + c;
        O[(size_t)(b * S_LEN + row) * (NHEADS * HEADD) + col] =
            f2bf(o_acc[dn][r] * invr[r]);
      }
  }
}

extern "C" void kernel_launch(void* const* d_in, const int* in_sizes, int n_in,
                              void* d_out, int out_size, void* d_ws, size_t ws_size,
                              hipStream_t stream) {
  const float* hs = (const float*)d_in[0];
  // d_in[1] = attention_mask: guaranteed causal; implemented analytically
  const float* wq = (const float*)d_in[2];
  const float* wk = (const float*)d_in[3];
  const float* wv = (const float*)d_in[4];
  const float* wo = (const float*)d_in[5];
  float* out = (float*)d_out;

  char* ws = (char*)d_ws;
  unsigned short* hs_bf = (unsigned short*)(ws);                        // 16 MB
  unsigned short* wqT  = (unsigned short*)(ws + ((size_t)16 << 20));    // 8 MB
  unsigned short* wkT  = (unsigned short*)(ws + ((size_t)24 << 20));    // 2 MB (K rows)
  unsigned short* wvT  = (unsigned short*)(ws + ((size_t)26 << 20));    // 2 MB (V rows, contiguous after wkT)
  unsigned short* woT  = (unsigned short*)(ws + ((size_t)28 << 20));    // 8 MB
  unsigned short* Qb   = (unsigned short*)(ws + ((size_t)36 << 20));    // 16 MB
  unsigned short* KVb  = (unsigned short*)(ws + ((size_t)52 << 20));    // 8 MB
  unsigned short* Ab   = (unsigned short*)(ws + ((size_t)60 << 20));    // 16 MB
  unsigned short* VtB  = (unsigned short*)(ws + ((size_t)76 << 20));    // 4 MB

  // 1. hs -> bf16
  int n4 = (B_SZ * S_LEN * HID) / 4;
  cvt_bf16_kernel<<<n4 / 256, 256, 0, stream>>>((const float4*)hs, (ushort4*)hs_bf, n4);

  // 2. weight transposes ([K][N] f32 -> [N][K] bf16); wq gets exp2-domain scale
  dim3 tb(32, 8);
  transpose_cvt_kernel<<<dim3(64, 64), tb, 0, stream>>>(wq, wqT, HID, NHEADS * HEADD,
                                                        QK_SCALE);
  transpose_cvt_kernel<<<dim3(16, 64), tb, 0, stream>>>(wk, wkT, HID, NKVH * HEADD,
                                                        1.0f);
  transpose_cvt_kernel<<<dim3(16, 64), tb, 0, stream>>>(wv, wvT, HID, NKVH * HEADD,
                                                        1.0f);
  transpose_cvt_kernel<<<dim3(64, 64), tb, 0, stream>>>(wo, woT, NHEADS * HEADD, HID,
                                                        1.0f);

  // 3. projections: Q (N=2048) and merged KV (N=1024; wkT||wvT contiguous)
  gemm_bt_kernel<unsigned short><<<32 * 16, 256, 0, stream>>>(
      hs_bf, wqT, Qb, B_SZ * S_LEN, NHEADS * HEADD, HID);
  gemm_bt_kernel<unsigned short><<<32 * 8, 256, 0, stream>>>(
      hs_bf, wkT, KVb, B_SZ * S_LEN, 1024, HID);

  // 3b. V -> V^T
  transpose_v_kernel<<<dim3(S_LEN / 32, HEADD / 32, B_SZ * NKVH), tb, 0, stream>>>(
      KVb, VtB);

  // 4. attention (MFMA flash, swapped QK^T + paired + dbuf via global_load_lds)
  mfma_attn_kernel<<<dim3(S_LEN / 128, NHEADS, B_SZ), 256, 0, stream>>>(
      Qb, KVb, VtB, Ab);

  // 5. output projection (fp32 out)
  gemm_bt_kernel<float><<<32 * 16, 256, 0, stream>>>(
      Ab, woT, out, B_SZ * S_LEN, HID, HID);
}

// Round 8
// 210.557 us; speedup vs baseline: 1.8031x; 1.0536x over previous
//
#include <hip/hip_runtime.h>
#include <hip/hip_bf16.h>
#include <type_traits>

// GroupedQueryAttention: B=2, S=2048, H=2048, NH=32, NKV=8, HD=64, G=4
// Pipeline:
//   1. hs -> bf16
//   2. transpose+cvt weights into wAllT = [wqT(scaled)|wkT|wvT] (3072x2048), woT
//   3. QKV = hs @ wAllT^T  (single GEMM, N=3072, dbuf single-barrier pipeline)
//   3b. V -> V^T  ([b][kvh][d][s]) for MFMA PV step
//   4. MFMA flash attention: swapped QK^T lane-local softmax, causal-paired
//      q-tiles, dbuf K/V via global_load_lds, defer-max (T13), setprio (T5)
//   5. out = attn@wo (fp32 out)

#define B_SZ 2
#define S_LEN 2048
#define HID 2048
#define NHEADS 32
#define NKVH 8
#define HEADD 64
#define QKV_N 3072
// 0.125 * log2(e): QK^T then directly exp2()
#define QK_SCALE 0.18033688f

typedef __attribute__((ext_vector_type(8))) short bf16x8;
typedef __attribute__((ext_vector_type(4))) float f32x4;

__device__ __forceinline__ float bf2f(unsigned short u) {
  union { unsigned int i; float f; } v;
  v.i = ((unsigned int)u) << 16;
  return v.f;
}
__device__ __forceinline__ unsigned short f2bf(float f) {
  union { float f; unsigned int i; } v;
  v.f = f;
  unsigned int r = v.i + 0x7fffu + ((v.i >> 16) & 1u);
  return (unsigned short)(r >> 16);
}
__device__ __forceinline__ unsigned short f2bf_rn(float f) {
  union { __hip_bfloat16 h; unsigned short u; } cv;
  cv.h = __float2bfloat16(f);
  return cv.u;
}
#if __has_builtin(__builtin_amdgcn_exp2f)
__device__ __forceinline__ float exp2v(float x) { return __builtin_amdgcn_exp2f(x); }
#else
__device__ __forceinline__ float exp2v(float x) { return exp2f(x); }
#endif
// async global->LDS, 16B per lane; lds dest = wave-uniform base + lane*16
__device__ __forceinline__ void gload_lds16(const unsigned short* g, unsigned short* l) {
  __builtin_amdgcn_global_load_lds(
      (const __attribute__((address_space(1))) unsigned int*)g,
      (__attribute__((address_space(3))) unsigned int*)l, 16, 0, 0);
}

// ---------------- elementwise f32 -> bf16 ----------------
__global__ void cvt_bf16_kernel(const float4* __restrict__ in,
                                ushort4* __restrict__ out, int n4) {
  int i = blockIdx.x * blockDim.x + threadIdx.x;
  if (i >= n4) return;
  float4 v = in[i];
  ushort4 o;
  o.x = f2bf(v.x); o.y = f2bf(v.y); o.z = f2bf(v.z); o.w = f2bf(v.w);
  out[i] = o;
}

// ---------------- transpose + cvt + scale: in[R][C] f32 -> out[C][R] bf16 ----
__global__ void transpose_cvt_kernel(const float* __restrict__ in,
                                     unsigned short* __restrict__ out,
                                     int R, int C, float scale) {
  __shared__ float tile[32][33];
  int c0 = blockIdx.x * 32, r0 = blockIdx.y * 32;
  int x = threadIdx.x, y = threadIdx.y;
#pragma unroll
  for (int i = 0; i < 32; i += 8)
    tile[y + i][x] = in[(size_t)(r0 + y + i) * C + c0 + x];
  __syncthreads();
#pragma unroll
  for (int i = 0; i < 32; i += 8)
    out[(size_t)(c0 + y + i) * R + r0 + x] = f2bf(tile[x][y + i] * scale);
}

// ---------------- bf16 transpose: QKV[b,s,2560+kvh*64+d] -> Vt[(b*8+kvh)*64+d][s] ----
__global__ void transpose_v_kernel(const unsigned short* __restrict__ QKV,
                                   unsigned short* __restrict__ Vt) {
  __shared__ unsigned short tile[32][33];
  int s0 = blockIdx.x * 32, d0 = blockIdx.y * 32;
  int bk = blockIdx.z;
  int b = bk >> 3, kvh = bk & 7;
  int x = threadIdx.x, y = threadIdx.y;
#pragma unroll
  for (int i = 0; i < 32; i += 8)
    tile[y + i][x] =
        QKV[(size_t)(b * S_LEN + s0 + y + i) * QKV_N + 2560 + kvh * HEADD + d0 + x];
  __syncthreads();
#pragma unroll
  for (int i = 0; i < 32; i += 8)
    Vt[((size_t)(b * NKVH + kvh) * HEADD + d0 + y + i) * S_LEN + s0 + x] =
        tile[x][y + i];
}

// ---------------- bf16 MFMA GEMM: C[M][N] = A[M][K] * Bt[N][K]^T ----------------
// 128x128 tile, BK=32, 4 waves. Double-buffered LDS, single barrier per K-step:
// stage(t+1 -> buf^1) || compute(buf) -> barrier(vmcnt drain) -> flip. (T3 min)
// Staging source pre-swizzled (slot ^ row&3) so b128 fragment reads are balanced.
// 1-D grid with XCD-aware swizzle (T1).
template <typename OutT>
__global__ __launch_bounds__(256) void gemm_bt_kernel(
    const unsigned short* __restrict__ A, const unsigned short* __restrict__ Bt,
    OutT* __restrict__ C, int M, int N, int K) {
  __shared__ unsigned short ldsA[2][128 * 32];
  __shared__ unsigned short ldsB[2][128 * 32];
  const int tid = threadIdx.x;
  const int wave = tid >> 6;
  const int lane = tid & 63;
  // XCD swizzle: nwg % 8 == 0 for all our launches (768 / 512)
  const int nwg = gridDim.x;
  const int orig = blockIdx.x;
  const int swz = (orig & 7) * (nwg >> 3) + (orig >> 3);
  const int ntn = N >> 7;
  const int m0 = (swz / ntn) << 7;
  const int n0 = (swz % ntn) << 7;
  const int wr = wave >> 1, wc = wave & 1;
  f32x4 acc[4][4] = {};

  // staging chunk c = tid + i*256: row=c>>2, slot=c&3; src k pre-swizzled
  size_t offA[2], offB[2];
#pragma unroll
  for (int i = 0; i < 2; ++i) {
    int cc = tid + i * 256;
    int row = cc >> 2, slot = cc & 3;
    int xk = (slot ^ (row & 3)) * 8;
    offA[i] = (size_t)(m0 + row) * K + xk;
    offB[i] = (size_t)(n0 + row) * K + xk;
  }
  const int rl = lane & 15, g = lane >> 4;
  const int nk = K >> 5;

  // prologue: stage k-step 0 into buf 0
#pragma unroll
  for (int i = 0; i < 2; ++i) {
    gload_lds16(A + offA[i], &ldsA[0][(wave * 64 + i * 256) * 8]);
    gload_lds16(Bt + offB[i], &ldsB[0][(wave * 64 + i * 256) * 8]);
  }
  __syncthreads();
  int cur = 0;

  for (int t = 0; t < nk; ++t) {
    if (t + 1 < nk) {
      const int k0 = (t + 1) << 5;
      const int nb = cur ^ 1;
#pragma unroll
      for (int i = 0; i < 2; ++i) {
        gload_lds16(A + offA[i] + k0, &ldsA[nb][(wave * 64 + i * 256) * 8]);
        gload_lds16(Bt + offB[i] + k0, &ldsB[nb][(wave * 64 + i * 256) * 8]);
      }
    }
    const int xs = (g ^ (rl & 3)) * 8;
    bf16x8 a[4], b[4];
#pragma unroll
    for (int mi = 0; mi < 4; ++mi)
      a[mi] = *(const bf16x8*)&ldsA[cur][(wr * 64 + mi * 16 + rl) * 32 + xs];
#pragma unroll
    for (int ni = 0; ni < 4; ++ni)
      b[ni] = *(const bf16x8*)&ldsB[cur][(wc * 64 + ni * 16 + rl) * 32 + xs];
#pragma unroll
    for (int mi = 0; mi < 4; ++mi)
#pragma unroll
      for (int ni = 0; ni < 4; ++ni)
        acc[mi][ni] =
            __builtin_amdgcn_mfma_f32_16x16x32_bf16(a[mi], b[ni], acc[mi][ni], 0, 0, 0);
    __syncthreads();  // drains staging vmcnt; buf[cur] reads are already in regs
    cur ^= 1;
  }
#pragma unroll
  for (int mi = 0; mi < 4; ++mi)
#pragma unroll
    for (int ni = 0; ni < 4; ++ni)
#pragma unroll
      for (int r = 0; r < 4; ++r) {
        int row = m0 + wr * 64 + mi * 16 + (lane >> 4) * 4 + r;
        int col = n0 + wc * 64 + ni * 16 + (lane & 15);
        float v = acc[mi][ni][r];
        if constexpr (std::is_same_v<OutT, unsigned short>)
          C[(size_t)row * N + col] = f2bf(v);
        else
          C[(size_t)row * N + col] = v;
      }
}

// ---------------- MFMA flash attention (swapped QK^T, lane-local softmax) ------
// grid: (16 pairs, NH, B). block 256 = 4 waves; wave w owns 16 q-rows.
// QK^T computed as mfma(K, Q) -> S^T[kv][q]: lane (g,c) holds q=c,
// kv = kn*16 + g*4 + r. Row softmax = in-lane tree + shfl_xor(16/32).
__global__ __launch_bounds__(256) void mfma_attn_kernel(
    const unsigned short* __restrict__ QKV,  // [B*S][3072]: Q | K | V
    const unsigned short* __restrict__ Vt,   // [(b*8+kvh)*64+d][S]
    unsigned short* __restrict__ O) {        // [B*S][NH*64]
  __shared__ unsigned short Ks[2][64 * 64];
  __shared__ unsigned short Vs[2][64 * 64];
  __shared__ unsigned short Pl[4 * 16 * 64];
  const int head = blockIdx.y, b = blockIdx.z;
  const int kvh = head >> 2;
  const int tid = threadIdx.x;
  const int w = tid >> 6, lane = tid & 63;
  const int c = lane & 15, g = lane >> 4;
  unsigned short* Plw = Pl + w * 1024;
  const int srow = tid >> 3, sslot = tid & 7;
  const int xslot = sslot ^ (srow & 7);

  // pre-swizzled per-lane global sources; LDS dest stays linear
  const unsigned short* Ksrc[2];
  const unsigned short* Vsrc[2];
#pragma unroll
  for (int i = 0; i < 2; ++i) {
    int row = srow + i * 32;
    Ksrc[i] = QKV + (size_t)(b * S_LEN + row) * QKV_N + 2048 + kvh * HEADD + xslot * 8;
    Vsrc[i] = Vt + ((size_t)(b * NKVH + kvh) * HEADD + row) * S_LEN + xslot * 8;
  }

  // prologue: stage tile 0 into buf 0
#pragma unroll
  for (int i = 0; i < 2; ++i) {
    gload_lds16(Ksrc[i], &Ks[0][(w * 64 + i * 256) * 8]);
    gload_lds16(Vsrc[i], &Vs[0][(w * 64 + i * 256) * 8]);
  }
  __syncthreads();
  int cur = 0;

  for (int ph = 0; ph < 2; ++ph) {
    const int qt = (ph == 0) ? (int)blockIdx.x : (S_LEN / 64 - 1) - (int)blockIdx.x;
    bf16x8 qf[2];
    {
      const unsigned short* qp =
          QKV + (size_t)(b * S_LEN + qt * 64 + w * 16 + c) * QKV_N + head * HEADD +
          g * 8;
      qf[0] = *(const bf16x8*)(qp);
      qf[1] = *(const bf16x8*)(qp + 32);
    }
    f32x4 o_acc[4] = {};       // O rows q = g*4+r, col d = dn*16+c
    float mstate = -INFINITY;  // per-lane: q-row c
    float lstate = 0.f;

    for (int t = 0; t <= qt; ++t) {
      const int kv0 = t * 64;
      const bool has_next = !(ph == 1 && t == qt);
      if (has_next) {
        const int kvn = (t < qt) ? kv0 + 64 : 0;  // next tile (or phase-1 tile 0)
        const int nb = cur ^ 1;
#pragma unroll
        for (int i = 0; i < 2; ++i) {
          gload_lds16(Ksrc[i] + (size_t)kvn * QKV_N, &Ks[nb][(w * 64 + i * 256) * 8]);
          gload_lds16(Vsrc[i] + kvn, &Vs[nb][(w * 64 + i * 256) * 8]);
        }
      }
      // ---- swapped QK^T: S^T[64 kv][16 q]; lane (g,c): q=c, kv=kn*16+g*4+r ----
      f32x4 s_acc[4] = {};
      __builtin_amdgcn_s_setprio(1);
#pragma unroll
      for (int ks = 0; ks < 2; ++ks)
#pragma unroll
        for (int kn = 0; kn < 4; ++kn) {
          bf16x8 kf = *(const bf16x8*)&Ks[cur][(kn * 16 + c) * 64 +
                                              (((ks * 4 + g) ^ (c & 7)) * 8)];
          s_acc[kn] =
              __builtin_amdgcn_mfma_f32_16x16x32_bf16(kf, qf[ks], s_acc[kn], 0, 0, 0);
        }
      __builtin_amdgcn_s_setprio(0);
      // ---- causal mask (lane-local) ----
      if (t == qt) {
        const int qg = qt * 64 + w * 16 + c;
#pragma unroll
        for (int kn = 0; kn < 4; ++kn)
#pragma unroll
          for (int r = 0; r < 4; ++r)
            if (kv0 + kn * 16 + g * 4 + r > qg) s_acc[kn][r] = -1e30f;
      }
      // ---- row max: in-lane tree + 2 shuffles ----
      float mk[4];
#pragma unroll
      for (int kn = 0; kn < 4; ++kn)
        mk[kn] = fmaxf(fmaxf(s_acc[kn][0], s_acc[kn][1]),
                       fmaxf(s_acc[kn][2], s_acc[kn][3]));
      float mx = fmaxf(fmaxf(mk[0], mk[1]), fmaxf(mk[2], mk[3]));
      mx = fmaxf(mx, __shfl_xor(mx, 16));
      mx = fmaxf(mx, __shfl_xor(mx, 32));
      // ---- defer-max (T13): rescale only when max grew past threshold ----
      if (__any(mx > mstate + 8.f)) {
        float nm = fmaxf(mstate, mx);
        float al = exp2v(mstate - nm);
        mstate = nm;
        lstate *= al;
        float alr[4];
#pragma unroll
        for (int r = 0; r < 4; ++r) alr[r] = __shfl(al, g * 4 + r);
#pragma unroll
        for (int dn = 0; dn < 4; ++dn)
#pragma unroll
          for (int r = 0; r < 4; ++r) o_acc[dn][r] *= alr[r];
      }
      // ---- P = exp2(s - m): in-lane, pack 4 bf16 per 8B LDS write ----
      float rs = 0.f;
#pragma unroll
      for (int kn = 0; kn < 4; ++kn) {
        union { unsigned short u[4]; uint2 v; } pk;
#pragma unroll
        for (int r = 0; r < 4; ++r) {
          float p = exp2v(s_acc[kn][r] - mstate);
          rs += p;
          pk.u[r] = f2bf_rn(p);
        }
        *(uint2*)&Plw[c * 64 + ((kn * 16 + g * 4) ^ ((c & 7) << 3))] = pk.v;
      }
      rs += __shfl_xor(rs, 16);
      rs += __shfl_xor(rs, 32);
      lstate += rs;
      // ---- PV: O[16 q][64 d] += P[16][64] @ V^T ----
      bf16x8 af[2];
#pragma unroll
      for (int ks2 = 0; ks2 < 2; ++ks2)
        af[ks2] = *(const bf16x8*)&Plw[c * 64 + ((ks2 * 32 + g * 8) ^ ((c & 7) << 3))];
      __builtin_amdgcn_s_setprio(1);
#pragma unroll
      for (int ks2 = 0; ks2 < 2; ++ks2)
#pragma unroll
        for (int dn = 0; dn < 4; ++dn) {
          bf16x8 vf = *(const bf16x8*)&Vs[cur][(dn * 16 + c) * 64 +
                                              (((ks2 * 4 + g) ^ (c & 7)) * 8)];
          o_acc[dn] =
              __builtin_amdgcn_mfma_f32_16x16x32_bf16(af[ks2], vf, o_acc[dn], 0, 0, 0);
        }
      __builtin_amdgcn_s_setprio(0);
      __syncthreads();  // drains staging vmcnt + all waves done reading buf[cur]
      if (has_next) cur ^= 1;
    }
    // ---- epilogue for this phase ----
    float inv = 1.0f / lstate;
    float invr[4];
#pragma unroll
    for (int r = 0; r < 4; ++r) invr[r] = __shfl(inv, g * 4 + r);
#pragma unroll
    for (int dn = 0; dn < 4; ++dn)
#pragma unroll
      for (int r = 0; r < 4; ++r) {
        int row = qt * 64 + w * 16 + g * 4 + r;
        int col = head * HEADD + dn * 16 + c;
        O[(size_t)(b * S_LEN + row) * (NHEADS * HEADD) + col] =
            f2bf(o_acc[dn][r] * invr[r]);
      }
  }
}

extern "C" void kernel_launch(void* const* d_in, const int* in_sizes, int n_in,
                              void* d_out, int out_size, void* d_ws, size_t ws_size,
                              hipStream_t stream) {
  const float* hs = (const float*)d_in[0];
  // d_in[1] = attention_mask: guaranteed causal; implemented analytically
  const float* wq = (const float*)d_in[2];
  const float* wk = (const float*)d_in[3];
  const float* wv = (const float*)d_in[4];
  const float* wo = (const float*)d_in[5];
  float* out = (float*)d_out;

  char* ws = (char*)d_ws;
  unsigned short* hs_bf = (unsigned short*)(ws);                        // 16 MB
  unsigned short* wAllT = (unsigned short*)(ws + ((size_t)16 << 20));   // 12 MB: wqT|wkT|wvT
  unsigned short* woT  = (unsigned short*)(ws + ((size_t)28 << 20));    // 8 MB
  unsigned short* QKV  = (unsigned short*)(ws + ((size_t)36 << 20));    // 24 MB
  unsigned short* Ab   = (unsigned short*)(ws + ((size_t)60 << 20));    // 16 MB
  unsigned short* VtB  = (unsigned short*)(ws + ((size_t)76 << 20));    // 4 MB

  // 1. hs -> bf16
  int n4 = (B_SZ * S_LEN * HID) / 4;
  cvt_bf16_kernel<<<n4 / 256, 256, 0, stream>>>((const float4*)hs, (ushort4*)hs_bf, n4);

  // 2. weight transposes into wAllT rows [0,2048)=wq(scaled), [2048,2560)=wk,
  //    [2560,3072)=wv; woT separate
  dim3 tb(32, 8);
  transpose_cvt_kernel<<<dim3(64, 64), tb, 0, stream>>>(wq, wAllT, HID, 2048, QK_SCALE);
  transpose_cvt_kernel<<<dim3(16, 64), tb, 0, stream>>>(wk, wAllT + (size_t)2048 * HID,
                                                        HID, 512, 1.0f);
  transpose_cvt_kernel<<<dim3(16, 64), tb, 0, stream>>>(wv, wAllT + (size_t)2560 * HID,
                                                        HID, 512, 1.0f);
  transpose_cvt_kernel<<<dim3(64, 64), tb, 0, stream>>>(wo, woT, NHEADS * HEADD, HID,
                                                        1.0f);

  // 3. merged QKV projection: M=4096, N=3072, K=2048 -> 768 blocks
  gemm_bt_kernel<unsigned short><<<32 * 24, 256, 0, stream>>>(
      hs_bf, wAllT, QKV, B_SZ * S_LEN, QKV_N, HID);

  // 3b. V -> V^T
  transpose_v_kernel<<<dim3(S_LEN / 32, HEADD / 32, B_SZ * NKVH), tb, 0, stream>>>(
      QKV, VtB);

  // 4. attention (MFMA flash, swapped QK^T + paired + dbuf via global_load_lds)
  mfma_attn_kernel<<<dim3(S_LEN / 128, NHEADS, B_SZ), 256, 0, stream>>>(
      QKV, VtB, Ab);

  // 5. output projection (fp32 out): M=4096, N=2048 -> 512 blocks
  gemm_bt_kernel<float><<<32 * 16, 256, 0, stream>>>(
      Ab, woT, out, B_SZ * S_LEN, HID, HID);
}